// Round 3
// baseline (352.855 us; speedup 1.0000x reference)
//
#include <hip/hip_runtime.h>

typedef unsigned int u32;

#define BS    16
#define HDIM  2048
#define QL    768
#define KVL   512
#define DR    64
#define DN    128
#define NH    16
#define NIH   8
#define IDXD  128
#define BLK   128
#define BPS   32
#define MAXKV 4096
#define TOPK  1024
#define NCH   32            // flash chunks per batch (32 rows each)

// ---------- 1. down-proj partials: cols [0:768|768:1344|1344:1472] ----------
// grid (46 col-tiles of 32, 16 k-splits of 128), 256 thr = 32 cols x 8 kgroups
__global__ void k_dproj(const float* __restrict__ x, const float* __restrict__ w_dq,
                        const float* __restrict__ w_dkv, const float* __restrict__ w_ik,
                        float* __restrict__ dpart){
  int tile = blockIdx.x, ks = blockIdx.y, t = threadIdx.x;
  __shared__ float xs[16*128];          // 8 KB
  __shared__ float sred[8*32*17];       // 17 KB, padded
  int k0 = ks*128;
  for (int idx=t; idx<16*128; idx+=256){
    int bb=idx>>7, kk=idx&127;
    xs[idx] = x[bb*HDIM + k0 + kk];
  }
  const float* wp; int ld, c0, gbase;
  if (tile < 24){ wp=w_dq;  ld=768; c0=tile*32;      gbase=0; }
  else if (tile < 42){ wp=w_dkv; ld=576; c0=(tile-24)*32; gbase=768; }
  else { wp=w_ik;  ld=128; c0=(tile-42)*32; gbase=1344; }
  int cl = t&31, kg = t>>5;
  int col = c0 + cl;
  __syncthreads();
  float acc[16];
  #pragma unroll
  for (int bb=0;bb<16;bb++) acc[bb]=0.f;
  const float* wb = wp + (size_t)(k0 + kg*16)*ld + col;
  #pragma unroll 4
  for (int kk=0; kk<16; kk++){
    float wv = wb[(size_t)kk*ld];
    int kx = kg*16+kk;
    #pragma unroll
    for (int bb=0; bb<16; bb++) acc[bb] += xs[bb*128+kx]*wv;
  }
  #pragma unroll
  for (int bb=0;bb<16;bb++) sred[(kg*32+cl)*17+bb] = acc[bb];
  __syncthreads();
  for (int r=0; r<2; r++){
    int o = r*256 + t;
    int bb = o>>5, cl2 = o&31;
    float s=0.f;
    #pragma unroll
    for (int kg2=0; kg2<8; kg2++) s += sred[(kg2*32+cl2)*17+bb];
    dpart[((size_t)ks*16 + bb)*1472 + gbase + c0 + cl2] = s;
  }
}

// ---------- 2. finalize norms; NEW cache rows go to workspace (inputs stay clean) ----------
// grid (16 b, 3 sec), 256 thr. Arithmetic order bit-identical to previous version.
__global__ void k_dfin(const float* __restrict__ dpart, const float* __restrict__ g_cq,
                       const float* __restrict__ g_ckv, const float* __restrict__ sinp,
                       const float* __restrict__ cosp, const float* __restrict__ g_ik,
                       const float* __restrict__ b_ik,
                       float* __restrict__ cq, float* __restrict__ newkv,
                       float* __restrict__ newkr, float* __restrict__ newik){
  int b = blockIdx.x, sec = blockIdx.y, t = threadIdx.x;   // 256
  __shared__ float val[768];
  __shared__ float red[256];
  if (sec==0){
    for (int c=t; c<768; c+=256){
      float s = 0.f;
      for (int ks2=0; ks2<16; ks2++) s += dpart[((size_t)ks2*16+b)*1472 + c];
      val[c] = s;
    }
    __syncthreads();
    float c0v = val[t], c1v = val[t+256], c2v = val[t+512];
    red[t] = c0v*c0v + c1v*c1v + c2v*c2v;
    __syncthreads();
    for (int s=128;s>0;s>>=1){ if(t<s) red[t]+=red[t+s]; __syncthreads(); }
    float scq = 1.0f/sqrtf(red[0]/(float)QL + 1e-6f);
    cq[b*QL+t]     = c0v*scq*g_cq[t];
    cq[b*QL+t+256] = c1v*scq*g_cq[t+256];
    cq[b*QL+t+512] = c2v*scq*g_cq[t+512];
  } else if (sec==1){
    for (int c=t; c<576; c+=256){
      float s = 0.f;
      for (int ks2=0; ks2<16; ks2++) s += dpart[((size_t)ks2*16+b)*1472 + 768 + c];
      val[c] = s;
    }
    __syncthreads();
    float v0 = val[t], v1 = val[t+256];
    red[t] = v0*v0 + v1*v1;
    __syncthreads();
    for (int s=128;s>0;s>>=1){ if(t<s) red[t]+=red[t+s]; __syncthreads(); }
    float sckv = 1.0f/sqrtf(red[0]/(float)KVL + 1e-6f);
    newkv[(size_t)b*KVL + t]     = v0*sckv*g_ckv[t];
    newkv[(size_t)b*KVL + t+256] = v1*sckv*g_ckv[t+256];
    if (t<DR){
      float v = val[512+t];
      float rot = (t<32)? -val[512+t+32] : val[512+t-32];
      newkr[(size_t)b*DR + t] = v*cosp[b*DR+t] + rot*sinp[b*DR+t];
    }
  } else {
    for (int c=t; c<128; c+=256){
      float s = 0.f;
      for (int ks2=0; ks2<16; ks2++) s += dpart[((size_t)ks2*16+b)*1472 + 1344 + c];
      val[c] = s;
    }
    __syncthreads();
    red[t] = (t<128)? val[t] : 0.f;
    __syncthreads();
    for (int s=128;s>0;s>>=1){ if(t<s) red[t]+=red[t+s]; __syncthreads(); }
    float mean = red[0]/(float)IDXD;
    __syncthreads();
    float cc = (t<128)? (val[t]-mean) : 0.f;
    red[t] = cc*cc;
    __syncthreads();
    for (int s=128;s>0;s>>=1){ if(t<s) red[t]+=red[t+s]; __syncthreads(); }
    float var = red[0]/(float)IDXD;
    if (t<IDXD){
      newik[(size_t)b*IDXD + t] = cc/sqrtf(var+1e-6f)*g_ik[t] + b_ik[t];
    }
  }
}

// ---------- 3. q-level proj partials (w_uq_qr | w_idx_qb | w_idx_proj) ----------
// grid (129 col-tiles, 4 k-splits of 192), 256 thr = 32 cols x 8 kgroups of 24
__global__ void k_qall(const float* __restrict__ cq, const float* __restrict__ w_uq,
                       const float* __restrict__ w_qb, const float* __restrict__ w_pj,
                       float* __restrict__ qpart){
  int tile = blockIdx.x, ks = blockIdx.y, t = threadIdx.x;
  __shared__ float xs[16*192];          // 12 KB
  __shared__ float sred[8*32*17];       // 17 KB
  int k0 = ks*192;
  for (int idx=t; idx<16*192; idx+=256){
    int bb = idx/192, kk = idx - bb*192;
    xs[idx] = cq[bb*QL + k0 + kk];
  }
  const float* wp; int ld, c0, gbase, kind;
  if (tile < 96){ wp=w_uq; ld=3072; c0=tile*32; gbase=0; kind=0; }
  else if (tile < 128){ wp=w_qb; ld=1024; c0=(tile-96)*32; gbase=3072; kind=0; }
  else { wp=w_pj; ld=8; c0=0; gbase=4096; kind=1; }
  int cl = t&31, kg = t>>5;
  int col = c0 + cl;
  bool act = !(kind==1 && cl>=8);
  __syncthreads();
  float acc[16];
  #pragma unroll
  for (int bb=0;bb<16;bb++) acc[bb]=0.f;
  const float* wb = wp + (size_t)(k0 + kg*24)*ld + col;
  if (act){
    #pragma unroll 4
    for (int kk=0; kk<24; kk++){
      float wv = wb[(size_t)kk*ld];
      int kx = kg*24+kk;
      #pragma unroll
      for (int bb=0; bb<16; bb++) acc[bb] += xs[bb*192+kx]*wv;
    }
  }
  #pragma unroll
  for (int bb=0;bb<16;bb++) sred[(kg*32+cl)*17+bb] = acc[bb];
  __syncthreads();
  for (int r=0; r<2; r++){
    int o = r*256 + t;
    int bb = o>>5, cl2 = o&31;
    float s=0.f;
    #pragma unroll
    for (int kg2=0; kg2<8; kg2++) s += sred[(kg2*32+cl2)*17+bb];
    qpart[((size_t)ks*16 + bb)*4128 + gbase + c0 + cl2] = s;
  }
}

// ---------- 4. finalize q-level + fused q_lat GEMV ----------
// grid (16 b, 17 part), 256 thr. part<16: head h -> rope qpe + qlat = qn . w_uk[h].
// part 16: qi + hw. Partial-sum order bit-identical for qi/hw (upstream of top-k).
__global__ void k_qfin(const float* __restrict__ qpart, const float* __restrict__ sinp,
                       const float* __restrict__ cosp, const float* __restrict__ wuk,
                       float* __restrict__ qp, float* __restrict__ qlat,
                       float* __restrict__ qi, float* __restrict__ hw){
  int b=blockIdx.x, part=blockIdx.y, t=threadIdx.x;   // 256
  if (part<16){
    __shared__ float val[192];
    int h=part;
    if (t<192){
      int c = h*192 + t;
      float s=0.f;
      for (int ks=0; ks<4; ks++) s += qpart[((size_t)ks*16+b)*4128 + c];
      val[t]=s;
    }
    __syncthreads();
    if (t>=128 && t<192){
      int d=t-128;
      float v=val[t];
      float rot = (d<32)? -val[160+d] : val[96+d];
      qp[(b*NH+h)*DR+d] = v*cosp[b*DR+d] + rot*sinp[b*DR+d];
    }
    // qlat GEMV: this thread computes cols t and t+256
    float a0=0.f, a1=0.f;
    const float* w = wuk + (size_t)h*DN*KVL;
    #pragma unroll 4
    for (int d=0; d<128; d++){
      float qv = val[d];
      a0 += qv * w[(size_t)d*KVL + t];
      a1 += qv * w[(size_t)d*KVL + t + 256];
    }
    qlat[((size_t)b*NH+h)*KVL + t]       = a0;
    qlat[((size_t)b*NH+h)*KVL + t + 256] = a1;
  } else {
    for (int idx=t; idx<1032; idx+=256){
      int c = 3072+idx;
      float s=0.f;
      for (int ks=0; ks<4; ks++) s += qpart[((size_t)ks*16+b)*4128 + c];
      if (idx<1024) qi[b*1024 + idx] = s;
      else hw[b*NIH + idx-1024] = s;
    }
  }
}

// ---------- 5. index scores (float4 LDS path; per-score accumulation order preserved) ----------
// grid (16, 32), 256 thr
__global__ void k_isc(const float* __restrict__ qi, const float* __restrict__ hw,
                      const float* __restrict__ ikc, const int* __restrict__ btab,
                      const int* __restrict__ aseq, const int* __restrict__ cidx,
                      const float* __restrict__ newik, float* __restrict__ isc){
  int b=blockIdx.x, jb=blockIdx.y, t=threadIdx.x;
  __shared__ float K[64*132];       // 33.8 KB, pitch 132 floats (16B-aligned rows)
  __shared__ float qs[NIH*132];
  __shared__ float hs[NIH];
  __shared__ float red[64*4];
  int blk = btab[b*BPS+jb];
  int ci  = cidx[b];
  for (int idx=t; idx<NIH*IDXD; idx+=256){ int h2=idx>>7, d=idx&127; qs[h2*132+d]=qi[b*1024+idx]; }
  if (t<NIH) hs[t]=hw[b*NIH+t];
  const float4* k4   = (const float4*)(ikc + (size_t)blk*BLK*IDXD);
  const float4* nik4 = (const float4*)(newik + (size_t)b*IDXD);
  int as = aseq[b];
  int r = t>>2, hp = t&3;
  for (int half=0; half<2; half++){
    __syncthreads();
    for (int it=0; it<8; it++){
      int idx = it*256 + t;
      int rr = idx>>5, c4 = idx&31;
      int grow = blk*BLK + half*64 + rr;
      float4 v = (grow==ci)? nik4[c4] : k4[(half*64+rr)*32 + c4];
      ((float4*)&K[rr*132])[c4] = v;
    }
    __syncthreads();
    float s0=0.f, s1=0.f;
    const float4* Kr = (const float4*)&K[r*132];
    const float4* q0 = (const float4*)&qs[hp*132];
    const float4* q1 = (const float4*)&qs[(hp+4)*132];
    for (int d=0; d<32; d++){
      float4 kv=Kr[d], a=q0[d], c=q1[d];
      s0 += a.x*kv.x; s1 += c.x*kv.x;
      s0 += a.y*kv.y; s1 += c.y*kv.y;
      s0 += a.z*kv.z; s1 += c.z*kv.z;
      s0 += a.w*kv.w; s1 += c.w*kv.w;
    }
    red[r*4+hp] = hs[hp]*fmaxf(s0,0.f) + hs[hp+4]*fmaxf(s1,0.f);
    __syncthreads();
    if (t<64){
      float sc = (red[t*4]+red[t*4+1]+red[t*4+2]+red[t*4+3]) * 0.08838834764831845f;
      int n = jb*BLK + half*64 + t;
      if (n >= as) sc = -1e9f;
      isc[b*MAXKV + n] = sc;
    }
  }
}

// ---------- 6. top-1024 radix select: stride-1 su access (no 32-way bank conflict),
//             16-copy histogram (cuts same-bin atomic serialization) ----------
__global__ void k_topk(const float* __restrict__ isc, const int* __restrict__ btab,
                       int* __restrict__ selp, float* __restrict__ sels){
  int b=blockIdx.x, t=threadIdx.x;   // 256 thr = 4 waves
  int lane = t&63, wv = t>>6;
  __shared__ u32 su[MAXKV];          // 16 KB
  __shared__ u32 hist[16*256];       // 16 KB (16 copies)
  __shared__ u32 cum[256];
  __shared__ u32 wtot[4];
  __shared__ u32 sh_b;
  int hc = (t&15)*256;
  for (int j=0;j<16;j++){
    int i=j*256+t;
    u32 bits=__float_as_uint(isc[b*MAXKV+i]);
    su[i] = (bits & 0x80000000u) ? ~bits : (bits | 0x80000000u);
  }
  u32 prefix=0u, need=1024u;
  for (int shift=24; shift>=0; shift-=8){
    for (int j=t;j<16*256;j+=256) hist[j]=0u;
    __syncthreads();
    u32 hm = (shift==24)? 0u : (0xFFFFFFFFu << (shift+8));
    for (int j=0;j<16;j++){
      u32 u = su[j*256+t];
      if ((u & hm) == prefix) atomicAdd(&hist[hc + ((u>>shift)&255u)], 1u);
    }
    __syncthreads();
    int bin = wv*64+lane;
    u32 v = 0u;
    #pragma unroll
    for (int cpy=0;cpy<16;cpy++) v += hist[cpy*256+bin];
    for (int off=1; off<64; off<<=1){
      u32 tmp = __shfl_down(v, off);
      if (lane + off < 64) v += tmp;
    }
    if (lane==0) wtot[wv]=v;
    __syncthreads();
    u32 add=0u;
    for (int w2=wv+1; w2<4; w2++) add += wtot[w2];
    v += add;
    cum[bin] = v;
    __syncthreads();
    u32 nxt = (bin<255)? cum[bin+1] : 0u;
    if (v>=need && nxt<need) sh_b = (u32)bin;
    __syncthreads();
    u32 B = sh_b;
    u32 aboveB = (B<255u)? cum[B+1] : 0u;
    need -= aboveB;
    prefix |= (B<<shift);
    __syncthreads();
  }
  u32 T = prefix;
  u32 cG=0u,cE=0u;
  for (int j=0;j<16;j++){ u32 u=su[j*256+t]; cG += (u>T)?1u:0u; cE += (u==T)?1u:0u; }
  u32 packed = (cG<<16) | cE;
  u32 v = packed;
  for (int off=1; off<64; off<<=1){
    u32 tmp = __shfl_up(v, off);
    if (lane >= off) v += tmp;
  }
  if (lane==63) wtot[wv]=v;
  __syncthreads();
  u32 add=0u;
  for (int w2=0; w2<wv; w2++) add += wtot[w2];
  u32 excl = v + add - packed;
  u32 total = wtot[0]+wtot[1]+wtot[2]+wtot[3];
  u32 mGT = total>>16;
  u32 keepEq = 1024u - mGT;
  u32 gG = excl>>16, gE = excl&0xFFFFu;
  for (int j=0;j<16;j++){
    int i=j*256+t; u32 u=su[i];
    int slot=-1;
    if (u>T) slot=(int)(gG++);
    else if (u==T){ u32 r2=gE++; if (r2<keepEq) slot=(int)(mGT+r2); }
    if (slot>=0){
      int pos = btab[b*BPS + (i>>7)]*BLK + (i&127);
      selp[b*TOPK+slot]=pos;
      sels[b*TOPK+slot]=isc[b*MAXKV+i];
    }
  }
}

// ---------- 7. fused gather attention v3 (+ workspace-row substitution) ----------
// grid (32 ch, 16 b), 256 thr = 4 waves, 2 blocks/CU (LDS 72.5 KB).
__global__ __launch_bounds__(256, 2)
void k_fgat(const float* __restrict__ qlat, const float* __restrict__ qpe,
            const float* __restrict__ kvc, const float* __restrict__ krc,
            const int* __restrict__ selp, const float* __restrict__ sels,
            const int* __restrict__ cidx, const float* __restrict__ newkv,
            const float* __restrict__ newkr,
            float* __restrict__ opart, float* __restrict__ mch,
            float* __restrict__ lch){
  int ch=blockIdx.x, b=blockIdx.y, t=threadIdx.x;   // 256 thr
  __shared__ float K[32*580];        // 72.5 KB, row pitch 580 floats (576+4 pad)
  int lane31 = t&31;
  int sp_l   = selp[b*TOPK + ch*32 + lane31];
  float sv_l = sels[b*TOPK + ch*32 + lane31];
  int ci = cidx[b];
  const float4* kv4  = (const float4*)kvc;
  const float4* kr4  = (const float4*)krc;
  const float4* nkv4 = (const float4*)newkv;   // 128 float4 per batch
  const float4* nkr4 = (const float4*)newkr;   // 16 float4 per batch
  // gather 32 rows x 144 float4 into regs (18/thread), all loads in flight
  float4 rA[18];
  #pragma unroll
  for (int j=0;j<18;j++){
    int idx=j*256+t, r=idx/144, c=idx-r*144;
    int row = __shfl(sp_l, r, 64);
    const float4* src;
    if (c<128) src = (row==ci)? (nkv4 + (size_t)b*128 + c) : (kv4 + (size_t)row*128 + c);
    else       src = (row==ci)? (nkr4 + (size_t)b*16 + (c-128)) : (kr4 + (size_t)row*16 + (c-128));
    rA[j] = *src;
  }
  // q chunk for (head, kc): 9 float4 = 36 floats, loaded once
  int h = t>>4, kc = t&15;
  const float4* ql4 = (const float4*)(qlat + ((size_t)b*NH+h)*KVL);
  const float4* qp4 = (const float4*)(qpe  + ((size_t)b*NH+h)*DR);
  float4 qreg[9];
  #pragma unroll
  for (int j=0;j<9;j++){
    int g = kc*9 + j;
    qreg[j] = (g<128)? ql4[g] : qp4[g-128];
  }
  // stage K tile
  #pragma unroll
  for (int j=0;j<18;j++){
    int idx=j*256+t, r=idx/144, c=idx-r*144;
    ((float4*)&K[r*580])[c] = rA[j];
  }
  __syncthreads();
  // ---- QK: scores, distributed softmax ----
  const float scale = 0.07216878364870323f;   // 1/sqrt(192)
  float pa=0.f, pb=0.f;
  for (int r=0;r<32;r++){
    const float4* Kc = (const float4*)&K[r*580 + kc*36];
    float s=0.f;
    #pragma unroll
    for (int j=0;j<9;j++){
      float4 kv=Kc[j], q=qreg[j];
      s += kv.x*q.x + kv.y*q.y + kv.z*q.z + kv.w*q.w;
    }
    #pragma unroll
    for (int mm=1;mm<16;mm<<=1) s += __shfl_xor(s, mm, 16);
    float svr = __shfl(sv_l, r, 64);
    float val = (svr > -1e8f)? s*scale : -1e9f;
    if (r<16) pa = (kc==r)?      val : pa;
    else      pb = (kc==(r-16))? val : pb;
  }
  float m2 = fmaxf(pa, pb);
  #pragma unroll
  for (int mm=1;mm<16;mm<<=1) m2 = fmaxf(m2, __shfl_xor(m2, mm, 16));
  pa = expf(pa - m2); pb = expf(pb - m2);
  float l2 = pa + pb;
  #pragma unroll
  for (int mm=1;mm<16;mm<<=1) l2 += __shfl_xor(l2, mm, 16);
  // ---- PV: 4 heads per wave, lane covers cols [4*l6,4*l6+4) and [256+4*l6,...) ----
  int l6 = t&63;
  float4 a0[4], a1[4];
  #pragma unroll
  for (int hq=0;hq<4;hq++){
    a0[hq].x=a0[hq].y=a0[hq].z=a0[hq].w=0.f;
    a1[hq].x=a1[hq].y=a1[hq].z=a1[hq].w=0.f;
  }
  for (int r=0;r<32;r++){
    const float4* Vr = (const float4*)&K[r*580];
    float4 v0 = Vr[l6], v1 = Vr[64+l6];
    float ps = (r<16)? pa : pb;
    int srcl = (r&15);
    float p0 = __shfl(ps, srcl,      64);
    float p1 = __shfl(ps, 16+srcl,   64);
    float p2 = __shfl(ps, 32+srcl,   64);
    float p3 = __shfl(ps, 48+srcl,   64);
    a0[0].x+=p0*v0.x; a0[0].y+=p0*v0.y; a0[0].z+=p0*v0.z; a0[0].w+=p0*v0.w;
    a1[0].x+=p0*v1.x; a1[0].y+=p0*v1.y; a1[0].z+=p0*v1.z; a1[0].w+=p0*v1.w;
    a0[1].x+=p1*v0.x; a0[1].y+=p1*v0.y; a0[1].z+=p1*v0.z; a0[1].w+=p1*v0.w;
    a1[1].x+=p1*v1.x; a1[1].y+=p1*v1.y; a1[1].z+=p1*v1.z; a1[1].w+=p1*v1.w;
    a0[2].x+=p2*v0.x; a0[2].y+=p2*v0.y; a0[2].z+=p2*v0.z; a0[2].w+=p2*v0.w;
    a1[2].x+=p2*v1.x; a1[2].y+=p2*v1.y; a1[2].z+=p2*v1.z; a1[2].w+=p2*v1.w;
    a0[3].x+=p3*v0.x; a0[3].y+=p3*v0.y; a0[3].z+=p3*v0.z; a0[3].w+=p3*v0.w;
    a1[3].x+=p3*v1.x; a1[3].y+=p3*v1.y; a1[3].z+=p3*v1.z; a1[3].w+=p3*v1.w;
  }
  int wv = t>>6;
  #pragma unroll
  for (int hq=0;hq<4;hq++){
    int hh = wv*4 + hq;
    float4* dst = (float4*)(opart + (((size_t)(b*NCH+ch))*NH + hh)*KVL);
    dst[l6]    = a0[hq];
    dst[64+l6] = a1[hq];
  }
  if (kc==0){
    mch[(b*NCH+ch)*16 + h] = m2;
    lch[(b*NCH+ch)*16 + h] = l2;
  }
}

// ---------- 8. combine chunks + project with w_uk ----------
// grid (16 b, 16 h), 128 thr
__global__ void k_comb(const float* __restrict__ opart, const float* __restrict__ mch,
                       const float* __restrict__ lch, const float* __restrict__ wuk,
                       float* __restrict__ out){
  int b=blockIdx.x, h=blockIdx.y, t=threadIdx.x;
  __shared__ float sOl[KVL];
  __shared__ float sCoef[NCH];
  __shared__ float sInvL;
  if (t<NCH){
    float mv = mch[(b*NCH+t)*16+h];
    float lv = lch[(b*NCH+t)*16+h];
    float M = mv;
    for (int off=1; off<NCH; off<<=1) M = fmaxf(M, __shfl_xor(M, off, NCH));
    float coef = expf(mv - M);
    float Lp = lv*coef;
    for (int off=1; off<NCH; off<<=1) Lp += __shfl_xor(Lp, off, NCH);
    sCoef[t] = coef;
    if (t==0) sInvL = 1.0f/Lp;
  }
  __syncthreads();
  for (int c=t; c<KVL; c+=128){
    float s=0.f;
    for (int ch=0; ch<NCH; ch++)
      s += opart[(((size_t)(b*NCH+ch))*NH + h)*KVL + c] * sCoef[ch];
    sOl[c] = s*sInvL;
  }
  __syncthreads();
  const float4* w4 = (const float4*)(wuk + ((size_t)(h*DN)+t)*KVL);
  const float4* o4 = (const float4*)sOl;
  float a=0.f;
  for (int v=0; v<128; v++){
    float4 w = w4[v]; float4 o = o4[v];
    a += w.x*o.x + w.y*o.y + w.z*o.z + w.w*o.w;
  }
  out[b*(NH*DN) + h*DN + t] = a;
}

extern "C" void kernel_launch(void* const* d_in, const int* in_sizes, int n_in,
                              void* d_out, int out_size, void* d_ws, size_t ws_size,
                              hipStream_t stream){
  const float* x        =(const float*)d_in[0];
  const float* w_dq     =(const float*)d_in[1];
  const float* w_uq_qr  =(const float*)d_in[2];
  const float* w_uk     =(const float*)d_in[3];
  const float* w_dkv_kr =(const float*)d_in[4];
  const float* g_cq     =(const float*)d_in[5];
  const float* g_ckv    =(const float*)d_in[6];
  const float* sinp     =(const float*)d_in[7];
  const float* cosp     =(const float*)d_in[8];
  const int*   cidx     =(const int*)d_in[9];
  const float* kvc      =(const float*)d_in[10];
  const float* krc      =(const float*)d_in[11];
  const int*   btab     =(const int*)d_in[12];
  const int*   aseq     =(const int*)d_in[13];
  const float* w_idx_qb =(const float*)d_in[14];
  const float* w_idx_k  =(const float*)d_in[15];
  const float* w_idx_pj =(const float*)d_in[16];
  const float* g_ik     =(const float*)d_in[17];
  const float* b_ik     =(const float*)d_in[18];
  const float* ikc      =(const float*)d_in[19];

  float* ws    = (float*)d_ws;
  float* cq    = ws;                   // 12288
  float* qpe   = ws + 12288;           // 16384
  float* qlat  = ws + 28672;           // 131072
  float* qi    = ws + 159744;          // 16384
  float* hw    = ws + 176128;          // 128
  float* isc   = ws + 176256;          // 65536
  int*   selp  = (int*)(ws + 241792);  // 16384
  float* sels  = ws + 258176;          // 16384
  float* dpart = ws + 274560;          // 16*16*1472 = 376832
  float* qpart = ws + 651392;          // 4*16*4128  = 264192
  float* mch   = ws + 915584;          // 8192
  float* lch   = ws + 923776;          // 8192
  float* opart = ws + 931968;          // 16*32*16*512 = 4194304
  float* newkv = ws + 5126272;         // 16*512 = 8192
  float* newkr = ws + 5134464;         // 16*64  = 1024
  float* newik = ws + 5135488;         // 16*128 = 2048

  k_dproj<<<dim3(46,16),  dim3(256),0,stream>>>(x,w_dq,w_dkv_kr,w_idx_k,dpart);
  k_dfin <<<dim3(BS,3),   dim3(256),0,stream>>>(dpart,g_cq,g_ckv,sinp,cosp,g_ik,b_ik,cq,newkv,newkr,newik);
  k_qall <<<dim3(129,4),  dim3(256),0,stream>>>(cq,w_uq_qr,w_idx_qb,w_idx_pj,qpart);
  k_qfin <<<dim3(BS,17),  dim3(256),0,stream>>>(qpart,sinp,cosp,w_uk,qpe,qlat,qi,hw);
  k_isc  <<<dim3(BS,BPS), dim3(256),0,stream>>>(qi,hw,ikc,btab,aseq,cidx,newik,isc);
  k_topk <<<dim3(BS),     dim3(256),0,stream>>>(isc,btab,selp,sels);
  k_fgat <<<dim3(NCH,BS), dim3(256),0,stream>>>(qlat,qpe,kvc,krc,selp,sels,cidx,newkv,newkr,opart,mch,lch);
  k_comb <<<dim3(BS,NH),  dim3(128),0,stream>>>(opart,mch,lch,w_uk,(float*)d_out);
}

// Round 4
// 331.728 us; speedup vs baseline: 1.0637x; 1.0637x over previous
//
#include <hip/hip_runtime.h>

typedef unsigned int u32;

#define BS    16
#define HDIM  2048
#define QL    768
#define KVL   512
#define DR    64
#define DN    128
#define NH    16
#define NIH   8
#define IDXD  128
#define BLK   128
#define BPS   32
#define MAXKV 4096
#define TOPK  1024
#define NCH   32            // flash chunks per batch (32 rows each)

// ---------- 1. down-proj partials: cols [0:768|768:1344|1344:1472] ----------
// grid (46 col-tiles of 32, 16 k-splits of 128), 256 thr = 32 cols x 8 kgroups
__global__ void k_dproj(const float* __restrict__ x, const float* __restrict__ w_dq,
                        const float* __restrict__ w_dkv, const float* __restrict__ w_ik,
                        float* __restrict__ dpart){
  int tile = blockIdx.x, ks = blockIdx.y, t = threadIdx.x;
  __shared__ float xs[16*128];          // 8 KB
  __shared__ float sred[8*32*17];       // 17 KB, padded
  int k0 = ks*128;
  for (int idx=t; idx<16*128; idx+=256){
    int bb=idx>>7, kk=idx&127;
    xs[idx] = x[bb*HDIM + k0 + kk];
  }
  const float* wp; int ld, c0, gbase;
  if (tile < 24){ wp=w_dq;  ld=768; c0=tile*32;      gbase=0; }
  else if (tile < 42){ wp=w_dkv; ld=576; c0=(tile-24)*32; gbase=768; }
  else { wp=w_ik;  ld=128; c0=(tile-42)*32; gbase=1344; }
  int cl = t&31, kg = t>>5;
  int col = c0 + cl;
  __syncthreads();
  float acc[16];
  #pragma unroll
  for (int bb=0;bb<16;bb++) acc[bb]=0.f;
  const float* wb = wp + (size_t)(k0 + kg*16)*ld + col;
  #pragma unroll 4
  for (int kk=0; kk<16; kk++){
    float wv = wb[(size_t)kk*ld];
    int kx = kg*16+kk;
    #pragma unroll
    for (int bb=0; bb<16; bb++) acc[bb] += xs[bb*128+kx]*wv;
  }
  #pragma unroll
  for (int bb=0;bb<16;bb++) sred[(kg*32+cl)*17+bb] = acc[bb];
  __syncthreads();
  for (int r=0; r<2; r++){
    int o = r*256 + t;
    int bb = o>>5, cl2 = o&31;
    float s=0.f;
    #pragma unroll
    for (int kg2=0; kg2<8; kg2++) s += sred[(kg2*32+cl2)*17+bb];
    dpart[((size_t)ks*16 + bb)*1472 + gbase + c0 + cl2] = s;
  }
}

// ---------- 2. finalize norms; NEW cache rows go to workspace (inputs stay clean) ----------
// grid (16 b, 3 sec), 256 thr.
__global__ void k_dfin(const float* __restrict__ dpart, const float* __restrict__ g_cq,
                       const float* __restrict__ g_ckv, const float* __restrict__ sinp,
                       const float* __restrict__ cosp, const float* __restrict__ g_ik,
                       const float* __restrict__ b_ik,
                       float* __restrict__ cq, float* __restrict__ newkv,
                       float* __restrict__ newkr, float* __restrict__ newik){
  int b = blockIdx.x, sec = blockIdx.y, t = threadIdx.x;   // 256
  __shared__ float val[768];
  __shared__ float red[256];
  if (sec==0){
    for (int c=t; c<768; c+=256){
      float s = 0.f;
      for (int ks2=0; ks2<16; ks2++) s += dpart[((size_t)ks2*16+b)*1472 + c];
      val[c] = s;
    }
    __syncthreads();
    float c0v = val[t], c1v = val[t+256], c2v = val[t+512];
    red[t] = c0v*c0v + c1v*c1v + c2v*c2v;
    __syncthreads();
    for (int s=128;s>0;s>>=1){ if(t<s) red[t]+=red[t+s]; __syncthreads(); }
    float scq = 1.0f/sqrtf(red[0]/(float)QL + 1e-6f);
    cq[b*QL+t]     = c0v*scq*g_cq[t];
    cq[b*QL+t+256] = c1v*scq*g_cq[t+256];
    cq[b*QL+t+512] = c2v*scq*g_cq[t+512];
  } else if (sec==1){
    for (int c=t; c<576; c+=256){
      float s = 0.f;
      for (int ks2=0; ks2<16; ks2++) s += dpart[((size_t)ks2*16+b)*1472 + 768 + c];
      val[c] = s;
    }
    __syncthreads();
    float v0 = val[t], v1 = val[t+256];
    red[t] = v0*v0 + v1*v1;
    __syncthreads();
    for (int s=128;s>0;s>>=1){ if(t<s) red[t]+=red[t+s]; __syncthreads(); }
    float sckv = 1.0f/sqrtf(red[0]/(float)KVL + 1e-6f);
    newkv[(size_t)b*KVL + t]     = v0*sckv*g_ckv[t];
    newkv[(size_t)b*KVL + t+256] = v1*sckv*g_ckv[t+256];
    if (t<DR){
      float v = val[512+t];
      float rot = (t<32)? -val[512+t+32] : val[512+t-32];
      newkr[(size_t)b*DR + t] = v*cosp[b*DR+t] + rot*sinp[b*DR+t];
    }
  } else {
    for (int c=t; c<128; c+=256){
      float s = 0.f;
      for (int ks2=0; ks2<16; ks2++) s += dpart[((size_t)ks2*16+b)*1472 + 1344 + c];
      val[c] = s;
    }
    __syncthreads();
    red[t] = (t<128)? val[t] : 0.f;
    __syncthreads();
    for (int s=128;s>0;s>>=1){ if(t<s) red[t]+=red[t+s]; __syncthreads(); }
    float mean = red[0]/(float)IDXD;
    __syncthreads();
    float cc = (t<128)? (val[t]-mean) : 0.f;
    red[t] = cc*cc;
    __syncthreads();
    for (int s=128;s>0;s>>=1){ if(t<s) red[t]+=red[t+s]; __syncthreads(); }
    float var = red[0]/(float)IDXD;
    if (t<IDXD){
      newik[(size_t)b*IDXD + t] = cc/sqrtf(var+1e-6f)*g_ik[t] + b_ik[t];
    }
  }
}

// ---------- 3. q-level proj partials (w_uq_qr | w_idx_qb | w_idx_proj) ----------
// grid (129 col-tiles, 4 k-splits of 192), 256 thr = 32 cols x 8 kgroups of 24
__global__ void k_qall(const float* __restrict__ cq, const float* __restrict__ w_uq,
                       const float* __restrict__ w_qb, const float* __restrict__ w_pj,
                       float* __restrict__ qpart){
  int tile = blockIdx.x, ks = blockIdx.y, t = threadIdx.x;
  __shared__ float xs[16*192];          // 12 KB
  __shared__ float sred[8*32*17];       // 17 KB
  int k0 = ks*192;
  for (int idx=t; idx<16*192; idx+=256){
    int bb = idx/192, kk = idx - bb*192;
    xs[idx] = cq[bb*QL + k0 + kk];
  }
  const float* wp; int ld, c0, gbase, kind;
  if (tile < 96){ wp=w_uq; ld=3072; c0=tile*32; gbase=0; kind=0; }
  else if (tile < 128){ wp=w_qb; ld=1024; c0=(tile-96)*32; gbase=3072; kind=0; }
  else { wp=w_pj; ld=8; c0=0; gbase=4096; kind=1; }
  int cl = t&31, kg = t>>5;
  int col = c0 + cl;
  bool act = !(kind==1 && cl>=8);
  __syncthreads();
  float acc[16];
  #pragma unroll
  for (int bb=0;bb<16;bb++) acc[bb]=0.f;
  const float* wb = wp + (size_t)(k0 + kg*24)*ld + col;
  if (act){
    #pragma unroll 4
    for (int kk=0; kk<24; kk++){
      float wv = wb[(size_t)kk*ld];
      int kx = kg*24+kk;
      #pragma unroll
      for (int bb=0; bb<16; bb++) acc[bb] += xs[bb*192+kx]*wv;
    }
  }
  #pragma unroll
  for (int bb=0;bb<16;bb++) sred[(kg*32+cl)*17+bb] = acc[bb];
  __syncthreads();
  for (int r=0; r<2; r++){
    int o = r*256 + t;
    int bb = o>>5, cl2 = o&31;
    float s=0.f;
    #pragma unroll
    for (int kg2=0; kg2<8; kg2++) s += sred[(kg2*32+cl2)*17+bb];
    qpart[((size_t)ks*16 + bb)*4128 + gbase + c0 + cl2] = s;
  }
}

// ---------- 4. finalize q-level (widened: per-head parts; R2 version) ----------
__global__ void k_qfin(const float* __restrict__ qpart, const float* __restrict__ sinp,
                       const float* __restrict__ cosp, float* __restrict__ qn,
                       float* __restrict__ qp, float* __restrict__ qi,
                       float* __restrict__ hw){
  int b=blockIdx.x, part=blockIdx.y, t=threadIdx.x;   // 256
  if (part<16){
    __shared__ float val[192];
    int h=part;
    if (t<192){
      int c = h*192 + t;
      float s=0.f;
      for (int ks=0; ks<4; ks++) s += qpart[((size_t)ks*16+b)*4128 + c];
      val[t]=s;
    }
    __syncthreads();
    if (t<192){
      int j=t;
      if (j<128) qn[(b*NH+h)*DN+j] = val[j];
      else {
        int d=j-128;
        float v=val[j];
        float rot = (d<32)? -val[160+d] : val[96+d];
        qp[(b*NH+h)*DR+d] = v*cosp[b*DR+d] + rot*sinp[b*DR+d];
      }
    }
  } else {
    for (int idx=t; idx<1032; idx+=256){
      int c = 3072+idx;
      float s=0.f;
      for (int ks=0; ks<4; ks++) s += qpart[((size_t)ks*16+b)*4128 + c];
      if (idx<1024) qi[b*1024 + idx] = s;
      else hw[b*NIH + idx-1024] = s;
    }
  }
}

// ---------- 5. q_lat = q_nope · w_uk (R2 version: w_uk read once) ----------
// grid (16 h, 8 col-tiles of 64), 256 thr = 64 cols x 4 kgroups of 32
__global__ void k_qlat(const float* __restrict__ qn, const float* __restrict__ wuk,
                       float* __restrict__ ql){
  int h=blockIdx.x, ct=blockIdx.y, t=threadIdx.x;
  __shared__ float qs[16*128];          // 8 KB
  __shared__ float sred[4*64*17];       // 17.4 KB
  for (int idx=t; idx<2048; idx+=256)
    qs[idx] = qn[((idx>>7)*NH+h)*DN + (idx&127)];
  int cl=t&63, kg=t>>6;
  int col=ct*64+cl;
  __syncthreads();
  float acc[16];
  #pragma unroll
  for (int bb=0;bb<16;bb++) acc[bb]=0.f;
  const float* wb = wuk + ((size_t)h*DN + kg*32)*KVL + col;
  #pragma unroll 4
  for (int kk=0;kk<32;kk++){
    float wv = wb[(size_t)kk*KVL];
    int kx = kg*32+kk;
    #pragma unroll
    for (int bb=0;bb<16;bb++) acc[bb]+=qs[bb*128+kx]*wv;
  }
  #pragma unroll
  for (int bb=0;bb<16;bb++) sred[(kg*64+cl)*17+bb]=acc[bb];
  __syncthreads();
  for (int r=0;r<4;r++){
    int o=r*256+t;
    int bb=o>>6, cl2=o&63;
    float s=0.f;
    #pragma unroll
    for (int kg2=0;kg2<4;kg2++) s+=sred[(kg2*64+cl2)*17+bb];
    ql[((size_t)bb*NH+h)*KVL + ct*64+cl2] = s;
  }
}

// ---------- 6. index scores (float4 LDS path; per-score accumulation order preserved) ----------
// grid (16, 32), 256 thr
__global__ void k_isc(const float* __restrict__ qi, const float* __restrict__ hw,
                      const float* __restrict__ ikc, const int* __restrict__ btab,
                      const int* __restrict__ aseq, const int* __restrict__ cidx,
                      const float* __restrict__ newik, float* __restrict__ isc){
  int b=blockIdx.x, jb=blockIdx.y, t=threadIdx.x;
  __shared__ float K[64*132];       // 33.8 KB
  __shared__ float qs[NIH*132];
  __shared__ float hs[NIH];
  __shared__ float red[64*4];
  int blk = btab[b*BPS+jb];
  int ci  = cidx[b];
  for (int idx=t; idx<NIH*IDXD; idx+=256){ int h2=idx>>7, d=idx&127; qs[h2*132+d]=qi[b*1024+idx]; }
  if (t<NIH) hs[t]=hw[b*NIH+t];
  const float4* k4   = (const float4*)(ikc + (size_t)blk*BLK*IDXD);
  const float4* nik4 = (const float4*)(newik + (size_t)b*IDXD);
  int as = aseq[b];
  int r = t>>2, hp = t&3;
  for (int half=0; half<2; half++){
    __syncthreads();
    for (int it=0; it<8; it++){
      int idx = it*256 + t;
      int rr = idx>>5, c4 = idx&31;
      int grow = blk*BLK + half*64 + rr;
      float4 v = (grow==ci)? nik4[c4] : k4[(half*64+rr)*32 + c4];
      ((float4*)&K[rr*132])[c4] = v;
    }
    __syncthreads();
    float s0=0.f, s1=0.f;
    const float4* Kr = (const float4*)&K[r*132];
    const float4* q0 = (const float4*)&qs[hp*132];
    const float4* q1 = (const float4*)&qs[(hp+4)*132];
    for (int d=0; d<32; d++){
      float4 kv=Kr[d], a=q0[d], c=q1[d];
      s0 += a.x*kv.x; s1 += c.x*kv.x;
      s0 += a.y*kv.y; s1 += c.y*kv.y;
      s0 += a.z*kv.z; s1 += c.z*kv.z;
      s0 += a.w*kv.w; s1 += c.w*kv.w;
    }
    red[r*4+hp] = hs[hp]*fmaxf(s0,0.f) + hs[hp+4]*fmaxf(s1,0.f);
    __syncthreads();
    if (t<64){
      float sc = (red[t*4]+red[t*4+1]+red[t*4+2]+red[t*4+3]) * 0.08838834764831845f;
      int n = jb*BLK + half*64 + t;
      if (n >= as) sc = -1e9f;
      isc[b*MAXKV + n] = sc;
    }
  }
}

// ---------- 7. top-1024 radix select, 1024 threads (4 elems/thread) ----------
__global__ __launch_bounds__(1024)
void k_topk(const float* __restrict__ isc, const int* __restrict__ btab,
            int* __restrict__ selp, float* __restrict__ sels){
  int b=blockIdx.x, t=threadIdx.x;   // 1024 thr = 16 waves
  int lane = t&63, wv = t>>6;
  __shared__ u32 su[MAXKV];          // 16 KB
  __shared__ u32 hist[16*256];       // 16 KB (16 copies)
  __shared__ u32 cum[256];
  __shared__ u32 wtot[16];
  __shared__ u32 sh_b;
  int hc = (t&15)*256;
  for (int j=0;j<4;j++){
    int i=j*1024+t;
    u32 bits=__float_as_uint(isc[b*MAXKV+i]);
    su[i] = (bits & 0x80000000u) ? ~bits : (bits | 0x80000000u);
  }
  u32 prefix=0u, need=1024u;
  for (int shift=24; shift>=0; shift-=8){
    for (int j=t;j<16*256;j+=1024) hist[j]=0u;
    __syncthreads();
    u32 hm = (shift==24)? 0u : (0xFFFFFFFFu << (shift+8));
    for (int j=0;j<4;j++){
      u32 u = su[j*1024+t];
      if ((u & hm) == prefix) atomicAdd(&hist[hc + ((u>>shift)&255u)], 1u);
    }
    __syncthreads();
    u32 v=0u;
    if (t<256){
      #pragma unroll
      for (int cpy=0;cpy<16;cpy++) v += hist[cpy*256+t];
      for (int off=1; off<64; off<<=1){
        u32 tmp = __shfl_down(v, off);
        if (lane + off < 64) v += tmp;
      }
      if (lane==0) wtot[wv]=v;
    }
    __syncthreads();
    if (t<256){
      u32 add=0u;
      for (int w2=wv+1; w2<4; w2++) add += wtot[w2];
      v += add;
      cum[t]=v;
    }
    __syncthreads();
    if (t<256){
      u32 nxt = (t<255)? cum[t+1] : 0u;
      if (v>=need && nxt<need) sh_b = (u32)t;
    }
    __syncthreads();
    u32 B = sh_b;
    u32 aboveB = (B<255u)? cum[B+1] : 0u;
    need -= aboveB;
    prefix |= (B<<shift);
    __syncthreads();
  }
  u32 T = prefix;
  u32 cG=0u,cE=0u;
  for (int j=0;j<4;j++){ u32 u=su[j*1024+t]; cG += (u>T)?1u:0u; cE += (u==T)?1u:0u; }
  u32 packed = (cG<<16) | cE;
  u32 v = packed;
  for (int off=1; off<64; off<<=1){
    u32 tmp = __shfl_up(v, off);
    if (lane >= off) v += tmp;
  }
  if (lane==63) wtot[wv]=v;
  __syncthreads();
  u32 add=0u;
  for (int w2=0; w2<wv; w2++) add += wtot[w2];
  u32 excl = v + add - packed;
  u32 total = 0u;
  #pragma unroll
  for (int w2=0; w2<16; w2++) total += wtot[w2];
  u32 mGT = total>>16;
  u32 keepEq = 1024u - mGT;
  u32 gG = excl>>16, gE = excl&0xFFFFu;
  for (int j=0;j<4;j++){
    int i=j*1024+t; u32 u=su[i];
    int slot=-1;
    if (u>T) slot=(int)(gG++);
    else if (u==T){ u32 r2=gE++; if (r2<keepEq) slot=(int)(mGT+r2); }
    if (slot>=0){
      int pos = btab[b*BPS + (i>>7)]*BLK + (i&127);
      selp[b*TOPK+slot]=pos;
      sels[b*TOPK+slot]=isc[b*MAXKV+i];
    }
  }
}

// ---------- 8. fused gather attention v4.1 ----------
// grid (32 ch, 16 b), 256 thr = 4 waves, 2 blocks/CU (LDS ~76 KB).
// QK: thread = (hp=t>>5, sub=(t>>4)&1, kc=t&15); q for heads hp & hp+8 in regs
// (18 f4, loaded once); each K chunk read ONCE serves TWO heads -> 144 LDS f4
// (half of v3). Scores retained in regs (kc==rl), softmax over 32-lane
// half-wave, P staged to sP[32][16] so PV reads one float4 per (row, 4 heads)
// instead of 4 shuffles. Per-score arithmetic order identical to v3.
__global__ __launch_bounds__(256, 2)
void k_fgat(const float* __restrict__ qlat, const float* __restrict__ qpe,
            const float* __restrict__ kvc, const float* __restrict__ krc,
            const int* __restrict__ selp, const float* __restrict__ sels,
            const int* __restrict__ cidx, const float* __restrict__ newkv,
            const float* __restrict__ newkr,
            float* __restrict__ opart, float* __restrict__ mch,
            float* __restrict__ lch){
  int ch=blockIdx.x, b=blockIdx.y, t=threadIdx.x;   // 256 thr
  __shared__ float K[32*580];        // 72.5 KB, row pitch 580 floats
  __shared__ float sP[32*16];        // 2 KB: P[row][head]
  int lane31 = t&31;
  int sp_l   = selp[b*TOPK + ch*32 + lane31];
  float sv_l = sels[b*TOPK + ch*32 + lane31];
  int ci = cidx[b];
  const float4* kv4  = (const float4*)kvc;
  const float4* kr4  = (const float4*)krc;
  const float4* nkv4 = (const float4*)newkv;
  const float4* nkr4 = (const float4*)newkr;
  // gather 32 rows x 144 float4 into regs (18/thread), contiguous idx layout
  float4 rA[18];
  #pragma unroll
  for (int j=0;j<18;j++){
    int idx=j*256+t, r=idx/144, c=idx-r*144;
    int row = __shfl(sp_l, r, 64);
    const float4* src;
    if (c<128) src = (row==ci)? (nkv4 + (size_t)b*128 + c) : (kv4 + (size_t)row*128 + c);
    else       src = (row==ci)? (nkr4 + (size_t)b*16 + (c-128)) : (kr4 + (size_t)row*16 + (c-128));
    rA[j] = *src;
  }
  // q for heads hp and hp+8, chunk kc: 18 f4, loaded once
  int hp = t>>5, sub = (t>>4)&1, kc = t&15;
  const float4* qlA = (const float4*)(qlat + ((size_t)b*NH+hp)*KVL);
  const float4* qpA = (const float4*)(qpe  + ((size_t)b*NH+hp)*DR);
  const float4* qlB = (const float4*)(qlat + ((size_t)b*NH+hp+8)*KVL);
  const float4* qpB = (const float4*)(qpe  + ((size_t)b*NH+hp+8)*DR);
  float4 qa[9], qb[9];
  #pragma unroll
  for (int j=0;j<9;j++){
    int g = kc*9 + j;
    qa[j] = (g<128)? qlA[g] : qpA[g-128];
    qb[j] = (g<128)? qlB[g] : qpB[g-128];
  }
  // stage K tile
  #pragma unroll
  for (int j=0;j<18;j++){
    int idx=j*256+t, r=idx/144, c=idx-r*144;
    ((float4*)&K[r*580])[c] = rA[j];
  }
  __syncthreads();
  // ---- QK: each K chunk read once for two heads ----
  const float scale = 0.07216878364870323f;   // 1/sqrt(192)
  float pa=0.f, pb=0.f;    // scores for row sub*16+kc, heads hp / hp+8
  for (int rl=0; rl<16; rl++){
    int r = sub*16 + rl;
    const float4* Kc = (const float4*)&K[r*580 + kc*36];
    float sA=0.f, sB=0.f;
    #pragma unroll
    for (int j=0;j<9;j++){
      float4 kv=Kc[j];
      sA += kv.x*qa[j].x + kv.y*qa[j].y + kv.z*qa[j].z + kv.w*qa[j].w;
      sB += kv.x*qb[j].x + kv.y*qb[j].y + kv.z*qb[j].z + kv.w*qb[j].w;
    }
    #pragma unroll
    for (int mm=1;mm<16;mm<<=1){
      sA += __shfl_xor(sA, mm, 16);
      sB += __shfl_xor(sB, mm, 16);
    }
    float svr = __shfl(sv_l, r, 64);
    float vA = (svr > -1e8f)? sA*scale : -1e9f;
    float vB = (svr > -1e8f)? sB*scale : -1e9f;
    if (kc==rl){ pa = vA; pb = vB; }
  }
  // ---- softmax over 32-lane half-wave (lane&31 == row) ----
  float mA = pa, mB = pb;
  #pragma unroll
  for (int mm=1;mm<32;mm<<=1){
    mA = fmaxf(mA, __shfl_xor(mA, mm, 32));
    mB = fmaxf(mB, __shfl_xor(mB, mm, 32));
  }
  pa = expf(pa - mA); pb = expf(pb - mB);
  float lA = pa, lB = pb;
  #pragma unroll
  for (int mm=1;mm<32;mm<<=1){
    lA += __shfl_xor(lA, mm, 32);
    lB += __shfl_xor(lB, mm, 32);
  }
  int r31 = sub*16 + kc;
  sP[r31*16 + hp]     = pa;
  sP[r31*16 + hp + 8] = pb;
  if (r31==0){
    mch[(b*NCH+ch)*16 + hp]     = mA;
    mch[(b*NCH+ch)*16 + hp + 8] = mB;
    lch[(b*NCH+ch)*16 + hp]     = lA;
    lch[(b*NCH+ch)*16 + hp + 8] = lB;
  }
  __syncthreads();
  // ---- PV: 4 heads per wave; one float4 P read per row ----
  int l6 = t&63, hg = t>>6;
  const float4* sP4 = (const float4*)sP;
  float4 a0[4], a1[4];
  #pragma unroll
  for (int hq=0;hq<4;hq++){
    a0[hq].x=a0[hq].y=a0[hq].z=a0[hq].w=0.f;
    a1[hq].x=a1[hq].y=a1[hq].z=a1[hq].w=0.f;
  }
  for (int r=0;r<32;r++){
    const float4* Vr = (const float4*)&K[r*580];
    float4 v0 = Vr[l6], v1 = Vr[64+l6];
    float4 p4 = sP4[r*4 + hg];
    a0[0].x+=p4.x*v0.x; a0[0].y+=p4.x*v0.y; a0[0].z+=p4.x*v0.z; a0[0].w+=p4.x*v0.w;
    a1[0].x+=p4.x*v1.x; a1[0].y+=p4.x*v1.y; a1[0].z+=p4.x*v1.z; a1[0].w+=p4.x*v1.w;
    a0[1].x+=p4.y*v0.x; a0[1].y+=p4.y*v0.y; a0[1].z+=p4.y*v0.z; a0[1].w+=p4.y*v0.w;
    a1[1].x+=p4.y*v1.x; a1[1].y+=p4.y*v1.y; a1[1].z+=p4.y*v1.z; a1[1].w+=p4.y*v1.w;
    a0[2].x+=p4.z*v0.x; a0[2].y+=p4.z*v0.y; a0[2].z+=p4.z*v0.z; a0[2].w+=p4.z*v0.w;
    a1[2].x+=p4.z*v1.x; a1[2].y+=p4.z*v1.y; a1[2].z+=p4.z*v1.z; a1[2].w+=p4.z*v1.w;
    a0[3].x+=p4.w*v0.x; a0[3].y+=p4.w*v0.y; a0[3].z+=p4.w*v0.z; a0[3].w+=p4.w*v0.w;
    a1[3].x+=p4.w*v1.x; a1[3].y+=p4.w*v1.y; a1[3].z+=p4.w*v1.z; a1[3].w+=p4.w*v1.w;
  }
  #pragma unroll
  for (int hq=0;hq<4;hq++){
    int hh = hg*4 + hq;
    float4* dst = (float4*)(opart + (((size_t)(b*NCH+ch))*NH + hh)*KVL);
    dst[l6]    = a0[hq];
    dst[64+l6] = a1[hq];
  }
}

// ---------- 9. combine chunks + project with w_uk ----------
// grid (16 b, 16 h), 128 thr
__global__ void k_comb(const float* __restrict__ opart, const float* __restrict__ mch,
                       const float* __restrict__ lch, const float* __restrict__ wuk,
                       float* __restrict__ out){
  int b=blockIdx.x, h=blockIdx.y, t=threadIdx.x;
  __shared__ float sOl[KVL];
  __shared__ float sCoef[NCH];
  __shared__ float sInvL;
  if (t<NCH){
    float mv = mch[(b*NCH+t)*16+h];
    float lv = lch[(b*NCH+t)*16+h];
    float M = mv;
    for (int off=1; off<NCH; off<<=1) M = fmaxf(M, __shfl_xor(M, off, NCH));
    float coef = expf(mv - M);
    float Lp = lv*coef;
    for (int off=1; off<NCH; off<<=1) Lp += __shfl_xor(Lp, off, NCH);
    sCoef[t] = coef;
    if (t==0) sInvL = 1.0f/Lp;
  }
  __syncthreads();
  for (int c=t; c<KVL; c+=128){
    float s=0.f;
    for (int ch=0; ch<NCH; ch++)
      s += opart[(((size_t)(b*NCH+ch))*NH + h)*KVL + c] * sCoef[ch];
    sOl[c] = s*sInvL;
  }
  __syncthreads();
  const float4* w4 = (const float4*)(wuk + ((size_t)(h*DN)+t)*KVL);
  const float4* o4 = (const float4*)sOl;
  float a=0.f;
  for (int v=0; v<128; v++){
    float4 w = w4[v]; float4 o = o4[v];
    a += w.x*o.x + w.y*o.y + w.z*o.z + w.w*o.w;
  }
  out[b*(NH*DN) + h*DN + t] = a;
}

extern "C" void kernel_launch(void* const* d_in, const int* in_sizes, int n_in,
                              void* d_out, int out_size, void* d_ws, size_t ws_size,
                              hipStream_t stream){
  const float* x        =(const float*)d_in[0];
  const float* w_dq     =(const float*)d_in[1];
  const float* w_uq_qr  =(const float*)d_in[2];
  const float* w_uk     =(const float*)d_in[3];
  const float* w_dkv_kr =(const float*)d_in[4];
  const float* g_cq     =(const float*)d_in[5];
  const float* g_ckv    =(const float*)d_in[6];
  const float* sinp     =(const float*)d_in[7];
  const float* cosp     =(const float*)d_in[8];
  const int*   cidx     =(const int*)d_in[9];
  const float* kvc      =(const float*)d_in[10];
  const float* krc      =(const float*)d_in[11];
  const int*   btab     =(const int*)d_in[12];
  const int*   aseq     =(const int*)d_in[13];
  const float* w_idx_qb =(const float*)d_in[14];
  const float* w_idx_k  =(const float*)d_in[15];
  const float* w_idx_pj =(const float*)d_in[16];
  const float* g_ik     =(const float*)d_in[17];
  const float* b_ik     =(const float*)d_in[18];
  const float* ikc      =(const float*)d_in[19];

  float* ws    = (float*)d_ws;
  float* cq    = ws;                   // 12288
  float* qnope = ws + 12288;           // 32768
  float* qpe   = ws + 45056;           // 16384
  float* qlat  = ws + 61440;           // 131072
  float* qi    = ws + 192512;          // 16384
  float* hw    = ws + 208896;          // 128
  float* isc   = ws + 209024;          // 65536
  int*   selp  = (int*)(ws + 274560);  // 16384
  float* sels  = ws + 290944;          // 16384
  float* dpart = ws + 307328;          // 376832
  float* qpart = ws + 684160;          // 264192
  float* mch   = ws + 948352;          // 8192
  float* lch   = ws + 956544;          // 8192
  float* opart = ws + 964736;          // 4194304
  float* newkv = ws + 5159040;         // 8192
  float* newkr = ws + 5167232;         // 1024
  float* newik = ws + 5168256;         // 2048

  k_dproj<<<dim3(46,16),  dim3(256),0,stream>>>(x,w_dq,w_dkv_kr,w_idx_k,dpart);
  k_dfin <<<dim3(BS,3),   dim3(256),0,stream>>>(dpart,g_cq,g_ckv,sinp,cosp,g_ik,b_ik,cq,newkv,newkr,newik);
  k_qall <<<dim3(129,4),  dim3(256),0,stream>>>(cq,w_uq_qr,w_idx_qb,w_idx_pj,qpart);
  k_qfin <<<dim3(BS,17),  dim3(256),0,stream>>>(qpart,sinp,cosp,qnope,qpe,qi,hw);
  k_qlat <<<dim3(16,8),   dim3(256),0,stream>>>(qnope,w_uk,qlat);
  k_isc  <<<dim3(BS,BPS), dim3(256),0,stream>>>(qi,hw,ikc,btab,aseq,cidx,newik,isc);
  k_topk <<<dim3(BS),     dim3(1024),0,stream>>>(isc,btab,selp,sels);
  k_fgat <<<dim3(NCH,BS), dim3(256),0,stream>>>(qlat,qpe,kvc,krc,selp,sels,cidx,newkv,newkr,opart,mch,lch);
  k_comb <<<dim3(BS,NH),  dim3(128),0,stream>>>(opart,mch,lch,w_uk,(float*)d_out);
}